// Round 5
// baseline (406.800 us; speedup 1.0000x reference)
//
#include <hip/hip_runtime.h>
#include <hip/hip_bf16.h>

typedef __bf16 bf16_t;
typedef __attribute__((ext_vector_type(8))) __bf16 bf16x8;
typedef __attribute__((ext_vector_type(4))) __bf16 bf16x4;
typedef __attribute__((ext_vector_type(4))) float floatx4;
typedef __attribute__((ext_vector_type(4))) int intx4;

#define NN 8192
#define FIN 256
#define FOUT 64
#define GAT_ALPHA 0.2f
#define NSLICE 8
#define JS (NN / NSLICE)     // 1024 j per slice
#define NJB (JS / 32)        // 32 MFMA K-tiles per slice
#define IB 64                // i-rows per block

// global_load_lds: wave-uniform LDS base, per-lane global src, 16B/lane
typedef const __attribute__((address_space(1))) void gv_t;
typedef __attribute__((address_space(3))) void lv_t;
#define GLOAD16(gp, lp) \
    __builtin_amdgcn_global_load_lds((gv_t*)(gp), (lv_t*)(lp), 16, 0, 0)

// ---------------------------------------------------------------------------
// Kernel A: h = input @ W (fp32 in -> bf16 MFMA). Stores h in MFMA
// B-FRAGMENT layout hTf[jb][ft][lane][8]: element (jb,ft,lq,lm,e) =
// h[jb*32 + lq*8 + e][ft*16 + lm]. A wave's B-frag load in kernel B is then
// a single contiguous 1KB global read. Also emits per-row E=exp(s),
// F=exp(0.2 s) for both attention halves.  (unchanged from R4)
// ---------------------------------------------------------------------------
__global__ __launch_bounds__(256) void gat_h_kernel(
    const float* __restrict__ input,    // [8192][256] fp32
    const float* __restrict__ W,        // [256][64] fp32
    const float* __restrict__ a,        // [128] fp32
    bf16_t* __restrict__ hTf,           // [256][4][64][8] bf16 frag layout
    float* __restrict__ e1g, float* __restrict__ f1g,
    float* __restrict__ e2g, float* __restrict__ f2g)
{
    alignas(16) __shared__ bf16_t in_lds[32][264];  // input tile, K contiguous
    alignas(16) __shared__ bf16_t wt_lds[64][264];  // W transposed [f][k]
    __shared__ float h_lds[32][65];                 // h tile fp32 for s1/s2

    const int t  = threadIdx.x;
    const int i0 = blockIdx.x * 32;

    #pragma unroll
    for (int v = 0; v < 8; v++) {
        int u  = v * 256 + t;
        int i  = u >> 6;
        int k4 = (u & 63) * 4;
        floatx4 x = *(const floatx4*)(input + (size_t)(i0 + i) * FIN + k4);
        bf16x4 b;
        #pragma unroll
        for (int e = 0; e < 4; e++) b[e] = (bf16_t)x[e];
        *(bf16x4*)(&in_lds[i][k4]) = b;
    }
    #pragma unroll
    for (int v = 0; v < 16; v++) {
        int u  = v * 256 + t;
        int k  = u >> 4;
        int f4 = (u & 15) * 4;
        floatx4 wv = *(const floatx4*)(W + k * FOUT + f4);
        #pragma unroll
        for (int e = 0; e < 4; e++) wt_lds[f4 + e][k] = (bf16_t)wv[e];
    }
    __syncthreads();

    const int wave = t >> 6;
    const int lane = t & 63;
    const int i16  = (wave & 1) * 16;
    const int f32  = (wave >> 1) * 32;
    const int lm   = lane & 15;
    const int lq   = lane >> 4;

    floatx4 acc0 = {0.f, 0.f, 0.f, 0.f};
    floatx4 acc1 = {0.f, 0.f, 0.f, 0.f};
    #pragma unroll
    for (int ks = 0; ks < 8; ks++) {
        int ko = ks * 32 + lq * 8;
        bf16x8 af = *(const bf16x8*)(&in_lds[i16 + lm][ko]);
        bf16x8 b0 = *(const bf16x8*)(&wt_lds[f32 + lm][ko]);
        bf16x8 b1 = *(const bf16x8*)(&wt_lds[f32 + 16 + lm][ko]);
        acc0 = __builtin_amdgcn_mfma_f32_16x16x32_bf16(af, b0, acc0, 0, 0, 0);
        acc1 = __builtin_amdgcn_mfma_f32_16x16x32_bf16(af, b1, acc1, 0, 0, 0);
    }

    // store hTf fragment layout. Lane holds h[i0+i16+lq*4+r][f32+c*16+lm];
    // frag coords: jb=i0/32, ft=f32/16+c, lq'=(i16+lq*4)/8, e=(lq&1)*4+r.
    {
        const int jb  = i0 >> 5;
        const int lqp = (i16 >> 3) + (lq >> 1);
        const int e0  = (lq & 1) * 4;
        #pragma unroll
        for (int c = 0; c < 2; c++) {
            floatx4 acc = c ? acc1 : acc0;
            int ft = (f32 >> 4) + c;
            bf16x4 hp;
            #pragma unroll
            for (int r = 0; r < 4; r++) hp[r] = (bf16_t)acc[r];
            *(bf16x4*)(hTf + (size_t)(((jb * 4 + ft) * 64 + lqp * 16 + lm) * 8 + e0)) = hp;
        }
    }
    // fp32 h tile into LDS for s1/s2
    #pragma unroll
    for (int c = 0; c < 2; c++) {
        floatx4 acc = c ? acc1 : acc0;
        #pragma unroll
        for (int r = 0; r < 4; r++)
            h_lds[i16 + lq * 4 + r][f32 + c * 16 + lm] = acc[r];
    }
    __syncthreads();

    if (t < 64) {
        int r   = t & 31;
        int sel = t >> 5;
        const float* av = a + sel * FOUT;
        float s = 0.f;
        #pragma unroll 8
        for (int f = 0; f < FOUT; f++) s += h_lds[r][f] * av[f];
        int gi = i0 + r;
        float E = expf(s);
        float F = expf(GAT_ALPHA * s);
        if (sel == 0) { e1g[gi] = E; f1g[gi] = F; }
        else          { e2g[gi] = E; f2g[gi] = F; }
    }
}

// ---------------------------------------------------------------------------
// Kernel P: pack adj (256 MB int32) -> row-major bitmask (8 MB).
// Pure streaming, fill-kernel-shaped: each thread reads 64 consecutive int32
// (16 x intx4, coalesced 16B/lane) and writes one uint64 (coalesced 8B/lane).
// bit (j%8) of byte (j/8) of row i  =  adj[i][j] > 0.
// ---------------------------------------------------------------------------
__global__ __launch_bounds__(256) void gat_pack_kernel(
    const int* __restrict__ adj,
    unsigned long long* __restrict__ bits)      // [8192][128] u64
{
    const int tid = blockIdx.x * 256 + threadIdx.x;   // 0 .. 2^20-1
    const int r   = tid >> 7;
    const int c   = tid & 127;                        // 64-j group in row
    const int* src = adj + (size_t)r * NN + c * 64;
    unsigned int lo = 0, hi = 0;
    #pragma unroll
    for (int u = 0; u < 8; u++) {
        intx4 v = *(const intx4*)(src + u * 4);
        #pragma unroll
        for (int e = 0; e < 4; e++)
            lo |= (v[e] > 0 ? 1u : 0u) << (u * 4 + e);
    }
    #pragma unroll
    for (int u = 0; u < 8; u++) {
        intx4 v = *(const intx4*)(src + 32 + u * 4);
        #pragma unroll
        for (int e = 0; e < 4; e++)
            hi |= (v[e] > 0 ? 1u : 0u) << (u * 4 + e);
    }
    bits[(size_t)r * 128 + c] = ((unsigned long long)hi << 32) | lo;
}

// ---------------------------------------------------------------------------
// Kernel B: attention + aggregation from the bitmask.
//  - block: 4 waves, IB=64 i-rows, JS=1024 j-slice; wave owns its own
//    16 rows x all 4 f-tiles (no frag redundancy)
//  - adj-bits: 8 KB/block, staged ONCE to LDS (source-XOR swizzle at 16B
//    granules so per-jb ds_read_b32 is 2-way bank conflict = free)
//  - e2/f2: 8 KB/block staged once. ONE __syncthreads total; no inner-loop
//    staging, no vmcnt choreography -- the 120us streaming wall is gone
//    because B no longer streams.
//  - hTf B-frags read directly from global (1 MB, L2/L1-hot, contiguous
//    1KB per wave-load)
//  - rowsum via 5th MFMA against all-ones B fragment
// LDS = 16 KB; grid (128, 8) = 1024 blocks = 4/CU resident, 16 waves/CU.
// ---------------------------------------------------------------------------
__global__ __launch_bounds__(256, 4) void gat_att_kernel(
    const unsigned char* __restrict__ bits,  // [8192][1024] bytes
    const bf16_t* __restrict__ hTf,          // [256][4][64][8] bf16 frag
    const float* __restrict__ e1g, const float* __restrict__ f1g,
    const float* __restrict__ e2g, const float* __restrict__ f2g,
    float* __restrict__ pacc,                // [NSLICE][8192][64] fp32
    float* __restrict__ prs)                 // [NSLICE][8192] fp32
{
    __shared__ unsigned char bitsL[IB][128];    // 8 KB, XOR-swizzled granules
    __shared__ float e2l[JS], f2l[JS];          // 8 KB

    const int t     = threadIdx.x;
    const int i0    = blockIdx.x * IB;
    const int slice = blockIdx.y;
    const int jbase = slice * JS;

    const int wave = t >> 6;
    const int lane = t & 63;
    const int lm   = lane & 15;
    const int lq   = lane >> 4;

    // ---- stage bits: rows i0..i0+63, slice window = 128 B/row.
    // LDS linear; source granule XORed with (row&7) so the read-side XOR
    // spreads banks (rule #21: swizzle source + read, keep dest linear).
    #pragma unroll
    for (int h = 0; h < 2; h++) {
        int r0 = wave * 16 + h * 8;            // 8 rows per instr
        int r  = r0 + (lane >> 3);
        int g  = (lane & 7) ^ (r & 7);
        GLOAD16(bits + (size_t)(i0 + r) * 1024 + slice * 128 + g * 16,
                &bitsL[r0][0]);
    }
    // ---- stage e2/f2 slice (1 KB per wave each, linear) ----
    {
        int o = wave * 256;
        GLOAD16(e2g + jbase + o + lane * 4, e2l + o);
        GLOAD16(f2g + jbase + o + lane * 4, f2l + o);
    }
    __syncthreads();    // drains vmcnt; the only barrier in the kernel

    const int   row = wave * 16 + lm;          // block-local A-frag row
    const float E1  = e1g[i0 + row];
    const float F1  = f1g[i0 + row];

    floatx4 acc0 = {0.f,0.f,0.f,0.f}, acc1 = {0.f,0.f,0.f,0.f};
    floatx4 acc2 = {0.f,0.f,0.f,0.f}, acc3 = {0.f,0.f,0.f,0.f};
    floatx4 accR = {0.f,0.f,0.f,0.f};
    bf16x8 ones;
    #pragma unroll
    for (int e = 0; e < 8; e++) ones[e] = (bf16_t)1.0f;

    const bf16_t* hslice = hTf + (size_t)slice * NJB * 2048 + (size_t)lane * 8;

    #pragma unroll 8
    for (int jb = 0; jb < NJB; jb++) {
        // word jb of this row's bit-window (granule-XOR read)
        int off = (((jb >> 2) ^ (row & 7)) << 4) | ((jb & 3) << 2);
        int wrd = *(const int*)(&bitsL[row][off]);
        unsigned bt = ((unsigned)wrd >> (lq * 8)) & 0xffu;   // v_bfe

        int jo = jb * 32 + lq * 8;
        floatx4 e2a = *(const floatx4*)(&e2l[jo]);
        floatx4 e2b = *(const floatx4*)(&e2l[jo + 4]);
        floatx4 f2a = *(const floatx4*)(&f2l[jo]);
        floatx4 f2b = *(const floatx4*)(&f2l[jo + 4]);
        bf16x8 frag;
        #pragma unroll
        for (int e = 0; e < 4; e++) {
            float w0 = fmaxf(E1 * e2a[e], F1 * f2a[e]);
            frag[e]     = (bt & (1u << e))       ? (bf16_t)w0 : (bf16_t)0.f;
            float w1 = fmaxf(E1 * e2b[e], F1 * f2b[e]);
            frag[e + 4] = (bt & (1u << (e + 4))) ? (bf16_t)w1 : (bf16_t)0.f;
        }

        // B-frags: contiguous 1KB per wave from frag-layout hT (L2/L1-hot)
        const bf16_t* hb = hslice + (size_t)jb * 2048;
        bf16x8 b0 = *(const bf16x8*)(hb);
        bf16x8 b1 = *(const bf16x8*)(hb + 512);
        bf16x8 b2 = *(const bf16x8*)(hb + 1024);
        bf16x8 b3 = *(const bf16x8*)(hb + 1536);
        acc0 = __builtin_amdgcn_mfma_f32_16x16x32_bf16(frag, b0, acc0, 0, 0, 0);
        acc1 = __builtin_amdgcn_mfma_f32_16x16x32_bf16(frag, b1, acc1, 0, 0, 0);
        acc2 = __builtin_amdgcn_mfma_f32_16x16x32_bf16(frag, b2, acc2, 0, 0, 0);
        acc3 = __builtin_amdgcn_mfma_f32_16x16x32_bf16(frag, b3, acc3, 0, 0, 0);
        accR = __builtin_amdgcn_mfma_f32_16x16x32_bf16(frag, ones, accR, 0, 0, 0);
    }

    // ---- rowsum write: accR col-independent; lm==0 lanes write ----
    if (lm == 0) {
        #pragma unroll
        for (int r = 0; r < 4; r++)
            prs[(size_t)slice * NN + i0 + wave * 16 + lq * 4 + r] = accR[r];
    }

    // ---- partial acc write: D layout col = ft*16+lm, row = lq*4+r ----
    float* pa = pacc + (size_t)slice * NN * FOUT
                     + (size_t)(i0 + wave * 16) * FOUT;
    #pragma unroll
    for (int ft = 0; ft < 4; ft++) {
        floatx4 acc = (ft == 0) ? acc0 : (ft == 1) ? acc1
                    : (ft == 2) ? acc2 : acc3;
        #pragma unroll
        for (int r = 0; r < 4; r++)
            pa[(size_t)(lq * 4 + r) * FOUT + ft * 16 + lm] = acc[r];
    }
}

// ---------------------------------------------------------------------------
// Kernel C: combine NSLICE partials, normalize, ELU, store fp32 output.
// ---------------------------------------------------------------------------
__global__ __launch_bounds__(256) void gat_combine_kernel(
    const float* __restrict__ pacc,     // [NSLICE][8192][64]
    const float* __restrict__ prs,      // [NSLICE][8192]
    float* __restrict__ out)            // [8192][64]
{
    int idx = blockIdx.x * 256 + threadIdx.x;
    int i   = idx >> 4;
    floatx4 s = {0.f, 0.f, 0.f, 0.f};
    float rs  = 0.f;
    #pragma unroll
    for (int p = 0; p < NSLICE; p++) {
        floatx4 v = *(const floatx4*)(pacc + (size_t)p * NN * FOUT + (size_t)idx * 4);
        s += v;
        rs += prs[p * NN + i];
    }
    float rinv = (rs > 0.f) ? 1.0f / rs : 0.f;
    floatx4 r;
    #pragma unroll
    for (int e = 0; e < 4; e++) {
        float x = s[e] * rinv;
        r[e] = (x > 0.f) ? x : (expf(x) - 1.0f);
    }
    *(floatx4*)(out + (size_t)idx * 4) = r;
}

// ---------------------------------------------------------------------------
extern "C" void kernel_launch(void* const* d_in, const int* in_sizes, int n_in,
                              void* d_out, int out_size, void* d_ws, size_t ws_size,
                              hipStream_t stream) {
    const float* input = (const float*)d_in[0];     // [8192][256] fp32
    const int*   adj   = (const int*)d_in[1];       // [8192][8192] int32
    const float* W     = (const float*)d_in[2];     // [256][64] fp32
    const float* a     = (const float*)d_in[3];     // [128] fp32
    float*       out   = (float*)d_out;             // [8192][64] fp32

    char* ws = (char*)d_ws;
    bf16_t* hTf = (bf16_t*)ws;                      // 1 MiB (frag layout)
    float*  e1g = (float*)(ws + (1 << 20));
    float*  f1g = e1g + NN;
    float*  e2g = f1g + NN;
    float*  f2g = e2g + NN;
    unsigned long long* bitsw = (unsigned long long*)(f2g + NN);   // 8 MiB
    float*  pacc = (float*)((char*)bitsw + NN * 128 * 8);  // 16 MiB
    float*  prs  = pacc + (size_t)NSLICE * NN * FOUT;      // 256 KiB

    gat_pack_kernel<<<NN * NN / 64 / 256, 256, 0, stream>>>(adj, bitsw);
    gat_h_kernel<<<NN / 32, 256, 0, stream>>>(input, W, a, hTf,
                                              e1g, f1g, e2g, f2g);
    dim3 gridB(NN / IB, NSLICE);
    gat_att_kernel<<<gridB, 256, 0, stream>>>((const unsigned char*)bitsw, hTf,
                                              e1g, f1g, e2g, f2g, pacc, prs);
    gat_combine_kernel<<<NN * FOUT / 4 / 256, 256, 0, stream>>>(pacc, prs, out);
}